// Round 1
// baseline (344.338 us; speedup 1.0000x reference)
//
#include <hip/hip_runtime.h>
#include <hip/hip_bf16.h>
#include <hip/hip_fp16.h>
#include <math.h>

// Problem constants (fixed-shape problem)
#define N_NODES 50000
#define FIN     32
#define HID     64
#define HC      128     // HEADS*HID
#define NE      800000
#define NET     850000  // NE + N self loops
#define NI      10000   // interface nodes
#define NG      50      // graphs
#define PB      8       // pooling blocks per graph

#define HBLK    ((NET + 255) / 256)   // histogram blocks in fused build kernel

typedef _Float16 half8 __attribute__((ext_vector_type(8)));
typedef float float4v __attribute__((ext_vector_type(4)));

__device__ __forceinline__ float lrelu(float x) { return fmaxf(x, 0.2f * x); }

// order-preserving float->uint encoding for atomicMax; 0 == "less than any float"
__device__ __forceinline__ unsigned fenc(float f) {
  unsigned u = __float_as_uint(f);
  return (u & 0x80000000u) ? ~u : (u | 0x80000000u);
}
__device__ __forceinline__ float fdec(unsigned u) {
  return (u & 0x80000000u) ? __uint_as_float(u ^ 0x80000000u) : __uint_as_float(~u);
}

__device__ __forceinline__ float rlf(float v, int l) {
  return __int_as_float(__builtin_amdgcn_readlane(__float_as_int(v), l));
}
__device__ __forceinline__ int rli(int v, int l) {
  return __builtin_amdgcn_readlane(v, l);
}

// ---------------- CSR build (unordered buckets, rank from histogram) ----------------
// Fused: blocks [0, HBLK) do the degree histogram + rank; the tail blocks do the
// per-graph interface ranges (independent work, one dispatch instead of two).
__global__ void k_hist_ranges(const int* __restrict__ ei, int* __restrict__ deg,
                              int* __restrict__ rank, const int* __restrict__ ipos,
                              const int* __restrict__ batch, int* __restrict__ gstart) {
  int b = blockIdx.x;
  if (b < HBLK) {
    int e = b * 256 + threadIdx.x;
    if (e >= NET) return;
    int d = (e < NE) ? ei[NE + e] : (e - NE);
    rank[e] = atomicAdd(&deg[d], 1);
  } else {
    int i = (b - HBLK) * 256 + threadIdx.x;
    if (i >= NI) return;
    int bi = batch[ipos[i]];
    int prev = (i > 0) ? batch[ipos[i - 1]] : -1;
    for (int g = prev + 1; g <= bi; g++) gstart[g] = i;
    if (i == NI - 1)
      for (int g = bi + 1; g <= NG; g++) gstart[g] = NI;
  }
}

__global__ void k_base(const int* __restrict__ deg, int* __restrict__ start,
                       int* __restrict__ gcur) {
  __shared__ int buf[256];
  __shared__ int basesh;
  int t = threadIdx.x;
  int i = blockIdx.x * 256 + t;
  int v = (i < N_NODES) ? deg[i] : 0;
  buf[t] = v; __syncthreads();
  for (int off = 1; off < 256; off <<= 1) {
    int a = (t >= off) ? buf[t - off] : 0;
    __syncthreads();
    buf[t] += a;
    __syncthreads();
  }
  if (t == 255) basesh = atomicAdd(gcur, buf[255]);
  __syncthreads();
  if (i < N_NODES) start[i] = basesh + buf[t] - v;
}

// edge record: 8B {src*256 (byte offset into xl2h), half2(1/ea.x, 1/ea.y)}
__global__ void k_scatter(const int* __restrict__ ei, const float* __restrict__ eattr,
                          const int* __restrict__ start, const int* __restrict__ rank,
                          int2* __restrict__ erec) {
  int e = blockIdx.x * blockDim.x + threadIdx.x;
  if (e >= NET) return;
  int s, d; float ex, ey;
  if (e < NE) {
    s = ei[e]; d = ei[NE + e];
    float2 ea = ((const float2*)eattr)[e];
    ex = 1.0f / ea.x; ey = 1.0f / ea.y;
  } else {
    s = d = e - NE; ex = 0.f; ey = 0.f;
  }
  int pos = start[d] + rank[e];
  __half2 ea2 = __floats2half2_rn(ex, ey);
  erec[pos] = make_int2(s << 8, *(int*)&ea2);
}

// ---------------- per-layer node linear via MFMA ----------------
// xl = h @ W  ([N x F] x [F x 128]) with fp16 inputs / fp32 accumulate.
// Block = 256 thr (4 waves), M-tile = 16 nodes (3125 blocks exactly).
// Wave w covers output cols [w*32, w*32+32) = two 16-wide N tiles; cols of one
// head per wave (w<2 -> head0). Epilogue: al/ar column-dots reduced in-register
// (shfl over the 16 cols) + LDS head-pairing to emit head-interleaved __half2.
// MFMA layouts (guide §3, m89/m91-verified): A[m=lane&15][k=(lane>>4)*8+j],
// B[k=(lane>>4)*8+j][n=lane&15], C/D[row=(lane>>4)*4+reg][col=lane&15].
template <int F>
__global__ __launch_bounds__(256) void k_linear_mfma(
    const float* __restrict__ h, const float* __restrict__ W,
    const float* __restrict__ attl, const float* __restrict__ attr,
    __half2* __restrict__ xl2h, float* __restrict__ al, float* __restrict__ ar) {
  __shared__ _Float16 hA[16 * F];
  __shared__ _Float16 hC[16 * 128];
  __shared__ float redl[16 * 4], redr[16 * 4];
  const int w = threadIdx.x >> 6, lane = threadIdx.x & 63;
  const int m = lane & 15, q = lane >> 4;
  const int n0 = blockIdx.x * 16;

  // stage A tile (16 consecutive node rows) as fp16
  for (int i = threadIdx.x; i < 16 * F; i += 256)
    hA[i] = (_Float16)h[(size_t)n0 * F + i];
  __syncthreads();

  half8 a0, a1;
#pragma unroll
  for (int j = 0; j < 8; j++) a0[j] = hA[m * F + q * 8 + j];
  if constexpr (F == 64) {
#pragma unroll
    for (int j = 0; j < 8; j++) a1[j] = hA[m * F + 32 + q * 8 + j];
  }

  const int c0 = w * 32;
  float4v acc[2];
  float pl[4] = {0.f, 0.f, 0.f, 0.f}, pr[4] = {0.f, 0.f, 0.f, 0.f};
#pragma unroll
  for (int t = 0; t < 2; t++) {
    const int colg = c0 + t * 16 + m;
    half8 b0;
#pragma unroll
    for (int j = 0; j < 8; j++) b0[j] = (_Float16)W[(q * 8 + j) * HC + colg];
    float4v z = {0.f, 0.f, 0.f, 0.f};
    acc[t] = __builtin_amdgcn_mfma_f32_16x16x32_f16(a0, b0, z, 0, 0, 0);
    if constexpr (F == 64) {
      half8 b1;
#pragma unroll
      for (int j = 0; j < 8; j++) b1[j] = (_Float16)W[(32 + q * 8 + j) * HC + colg];
      acc[t] = __builtin_amdgcn_mfma_f32_16x16x32_f16(a1, b1, acc[t], 0, 0, 0);
    }
    const float atl = attl[colg], atr = attr[colg];
#pragma unroll
    for (int reg = 0; reg < 4; reg++) {
      float val = acc[t][reg];
      hC[(q * 4 + reg) * 128 + colg] = (_Float16)val;
      pl[reg] += val * atl;
      pr[reg] += val * atr;
    }
  }
  // reduce attention dots over the 16 cols held within each quad
#pragma unroll
  for (int off = 1; off < 16; off <<= 1) {
#pragma unroll
    for (int reg = 0; reg < 4; reg++) {
      pl[reg] += __shfl_xor(pl[reg], off, 64);
      pr[reg] += __shfl_xor(pr[reg], off, 64);
    }
  }
  if (m == 0) {
#pragma unroll
    for (int reg = 0; reg < 4; reg++) {
      redl[(q * 4 + reg) * 4 + w] = pl[reg];
      redr[(q * 4 + reg) * 4 + w] = pr[reg];
    }
  }
  __syncthreads();
  if (threadIdx.x < 32) {
    int node = threadIdx.x >> 1, head = threadIdx.x & 1;
    al[(n0 + node) * 2 + head] = redl[node * 4 + head * 2] + redl[node * 4 + head * 2 + 1];
    ar[(n0 + node) * 2 + head] = redr[node * 4 + head * 2] + redr[node * 4 + head * 2 + 1];
  }
  for (int i = threadIdx.x; i < 16 * 64; i += 256) {
    int node = i >> 6, cc = i & 63;
    xl2h[(size_t)(n0 + node) * HID + cc] =
        __halves2half2(hC[node * 128 + cc], hC[node * 128 + 64 + cc]);
  }
}

// ---------------- per-layer edge aggregation ----------------
// TWO dst nodes per wave (A = lanes' score strip 0-31, B = 32-63):
//  - score phase: 32-lane strips per node (mean degree ~17 << 64, so a 64-lane
//    strip wasted 3/4 of the lanes; 32-lane strips waste only half).
//  - gather phase: interleaved 4-edge chunks of node A and node B -> two fully
//    independent readlane/gather/FMA chains in flight (2x memory-level
//    parallelism in the previously serial per-node loop).
//  - score-sum reduction: 5 shfl_xor steps within each 32-lane half (vs 6 over
//    64), then 12 broadcasts; ~21 shfl/node vs 36 before.
// Pad edges (j >= deg) carry p=0 / soff=0, so 4-chunk padding gathers node 0's
// row harmlessly with zero weight.
__global__ __launch_bounds__(256) void k_aggregate(
    const __half2* __restrict__ xl2h, const float* __restrict__ alp,
    const float2* __restrict__ ar2, const int* __restrict__ start,
    const int* __restrict__ degarr, const int2* __restrict__ erec,
    const float* __restrict__ eW2, const float* __restrict__ eb1,
    const float* __restrict__ bconv1, float* __restrict__ hout) {
  const int gid0 = blockIdx.x * 8 + (threadIdx.x >> 6) * 2;
  const int lane = threadIdx.x & 63;
  const int l32 = lane & 31;
  const int half = lane >> 5;
  const int lane4 = lane << 2;
  const int gidH = gid0 + half;
  const int o0H = start[gidH];
  const int degH = degarr[gidH];
  const float2 arvH = ar2[gidH];
  const char* xbase = (const char*)xl2h;
  const char* albase = (const char*)alp;

  const int degA = rli(degH, 0);
  const int degB = rli(degH, 32);
  const int degmax = max(degA, degB);

  // per-node accumulators, 2 chains each for FMA ILP
  float aA0 = 0.f, aA1 = 0.f, bA0 = 0.f, bA1 = 0.f;
  float aB0 = 0.f, aB1 = 0.f, bB0 = 0.f, bB1 = 0.f;
  float ld0 = 0.f, ld1 = 0.f, lex0 = 0.f, ley0 = 0.f, lex1 = 0.f, ley1 = 0.f;

  for (int base = 0; base < degmax; base += 32) {
    int j = base + l32;
    int soff = 0; float p0 = 0.f, p1 = 0.f;
    if (j < degH) {
      int2 r = erec[o0H + j];
      soff = r.x;
      float2 eaf = __half22float2(*(__half2*)&r.y);
      float2 alv = *(const float2*)(albase + (soff >> 5));
      p0 = __expf(lrelu(alv.x + arvH.x));
      p1 = __expf(lrelu(alv.y + arvH.y));
      ld0 += p0; ld1 += p1;
      lex0 += p0 * eaf.x; ley0 += p0 * eaf.y;
      lex1 += p1 * eaf.x; ley1 += p1 * eaf.y;
    }
    int lenA = min(32, degA - base); lenA = max(lenA, 0);
    int lenB = min(32, degB - base); lenB = max(lenB, 0);
    int lenA4 = (lenA + 3) & ~3;
    int lenB4 = (lenB + 3) & ~3;
    int len = max(lenA4, lenB4);
    for (int j2 = 0; j2 < len; j2 += 4) {
      if (j2 < lenA4) {
        float2 x0 = __half22float2(*(const __half2*)(xbase + rli(soff, j2)     + lane4));
        float2 x1 = __half22float2(*(const __half2*)(xbase + rli(soff, j2 + 1) + lane4));
        float2 x2 = __half22float2(*(const __half2*)(xbase + rli(soff, j2 + 2) + lane4));
        float2 x3 = __half22float2(*(const __half2*)(xbase + rli(soff, j2 + 3) + lane4));
        aA0 += rlf(p0, j2)     * x0.x; aA1 += rlf(p1, j2)     * x0.y;
        bA0 += rlf(p0, j2 + 1) * x1.x; bA1 += rlf(p1, j2 + 1) * x1.y;
        aA0 += rlf(p0, j2 + 2) * x2.x; aA1 += rlf(p1, j2 + 2) * x2.y;
        bA0 += rlf(p0, j2 + 3) * x3.x; bA1 += rlf(p1, j2 + 3) * x3.y;
      }
      if (j2 < lenB4) {
        float2 x4 = __half22float2(*(const __half2*)(xbase + rli(soff, 32 + j2)     + lane4));
        float2 x5 = __half22float2(*(const __half2*)(xbase + rli(soff, 32 + j2 + 1) + lane4));
        float2 x6 = __half22float2(*(const __half2*)(xbase + rli(soff, 32 + j2 + 2) + lane4));
        float2 x7 = __half22float2(*(const __half2*)(xbase + rli(soff, 32 + j2 + 3) + lane4));
        aB0 += rlf(p0, 32 + j2)     * x4.x; aB1 += rlf(p1, 32 + j2)     * x4.y;
        bB0 += rlf(p0, 32 + j2 + 1) * x5.x; bB1 += rlf(p1, 32 + j2 + 1) * x5.y;
        aB0 += rlf(p0, 32 + j2 + 2) * x6.x; aB1 += rlf(p1, 32 + j2 + 2) * x6.y;
        bB0 += rlf(p0, 32 + j2 + 3) * x7.x; bB1 += rlf(p1, 32 + j2 + 3) * x7.y;
      }
    }
  }
  float accA0 = aA0 + bA0, accA1 = aA1 + bA1;
  float accB0 = aB0 + bB0, accB1 = aB1 + bB1;
  // reduce the 6 score sums within each 32-lane half (offsets stay in-half)
#pragma unroll
  for (int off = 16; off; off >>= 1) {
    ld0  += __shfl_xor(ld0, off, 64);
    ld1  += __shfl_xor(ld1, off, 64);
    lex0 += __shfl_xor(lex0, off, 64);
    ley0 += __shfl_xor(ley0, off, 64);
    lex1 += __shfl_xor(lex1, off, 64);
    ley1 += __shfl_xor(ley1, off, 64);
  }
  // broadcast each node's totals to all 64 lanes
  float ld0A  = __shfl(ld0,  l32, 64), ld0B  = __shfl(ld0,  32 + l32, 64);
  float ld1A  = __shfl(ld1,  l32, 64), ld1B  = __shfl(ld1,  32 + l32, 64);
  float lex0A = __shfl(lex0, l32, 64), lex0B = __shfl(lex0, 32 + l32, 64);
  float ley0A = __shfl(ley0, l32, 64), ley0B = __shfl(ley0, 32 + l32, 64);
  float lex1A = __shfl(lex1, l32, 64), lex1B = __shfl(lex1, 32 + l32, 64);
  float ley1A = __shfl(ley1, l32, 64), ley1B = __shfl(ley1, 32 + l32, 64);

  const float w00 = eW2[lane],      w01 = eW2[HC + lane],      b0v = eb1[lane];
  const float w10 = eW2[64 + lane], w11 = eW2[HC + 64 + lane], b1v = eb1[64 + lane];
  const float bc = bconv1[lane];

  float tA0 = accA0 + w00 * lex0A + w01 * ley0A + b0v * ld0A;
  float tA1 = accA1 + w10 * lex1A + w11 * ley1A + b1v * ld1A;
  float tB0 = accB0 + w00 * lex0B + w01 * ley0B + b0v * ld0B;
  float tB1 = accB1 + w10 * lex1B + w11 * ley1B + b1v * ld1B;
  float rA = 0.5f * (tA0 / (ld0A + 1e-16f) + tA1 / (ld1A + 1e-16f)) + bc;
  float rB = 0.5f * (tB0 / (ld0B + 1e-16f) + tB1 / (ld1B + 1e-16f)) + bc;
  hout[(size_t)gid0 * HID + lane] = tanhf(rA);
  hout[(size_t)(gid0 + 1) * HID + lane] = tanhf(rB);
}

// ---------------- pooling ----------------
__global__ void k_pool(const float* __restrict__ h0, const float* __restrict__ h1,
                       const float* __restrict__ h2, const int* __restrict__ ipos,
                       const int* __restrict__ gstart, const float* __restrict__ gate_w,
                       const float* __restrict__ gate_b, float* __restrict__ add,
                       unsigned* __restrict__ mxE, float* __restrict__ cnt,
                       float* __restrict__ attp, float* __restrict__ aden) {
  __shared__ float red[4][3 * HID + 2];
  const int g = blockIdx.x / PB, m = blockIdx.x % PB;
  const int w = threadIdx.x >> 6, lane = threadIdx.x & 63;
  const int s0 = gstart[g], s1 = gstart[g + 1];
  const int len = s1 - s0;
  const int b0 = s0 + (len * m) / PB;
  const int b1 = s0 + (len * (m + 1)) / PB;
  const float gwv = gate_w[lane];
  const float gbv = gate_b[0];

  float padd = 0.f, pmax = -1e30f, pattp = 0.f, paden = 0.f, pcnt = 0.f;
  for (int i = b0 + w; i < b1; i += 4) {
    size_t node = (size_t)ipos[i] * HID + lane;
    float v = fmaxf(fmaxf(h0[node], h1[node]), h2[node]);
    padd += v;
    pmax = fmaxf(pmax, v);
    float gv = v * gwv;
#pragma unroll
    for (int off = 32; off; off >>= 1) gv += __shfl_xor(gv, off, 64);
    float e = __expf(gv + gbv);   // |gate| << 88: exp-safe without max shift
    pattp += e * v;
    paden += e;   // wave-uniform
    pcnt += 1.f;
  }
  red[w][lane] = padd;
  red[w][HID + lane] = pmax;
  red[w][2 * HID + lane] = pattp;
  if (lane == 0) { red[w][3 * HID] = paden; red[w][3 * HID + 1] = pcnt; }
  __syncthreads();
  if (w == 0) {
    float addv  = red[0][lane] + red[1][lane] + red[2][lane] + red[3][lane];
    float maxv  = fmaxf(fmaxf(red[0][HID + lane], red[1][HID + lane]),
                        fmaxf(red[2][HID + lane], red[3][HID + lane]));
    float attpv = red[0][2 * HID + lane] + red[1][2 * HID + lane] +
                  red[2][2 * HID + lane] + red[3][2 * HID + lane];
    atomicAdd(&add[g * HID + lane], addv);
    atomicMax(&mxE[g * HID + lane], fenc(maxv));
    atomicAdd(&attp[g * HID + lane], attpv);
    if (lane == 0) {
      atomicAdd(&aden[g], red[0][3 * HID] + red[1][3 * HID] + red[2][3 * HID] + red[3][3 * HID]);
      atomicAdd(&cnt[g],  red[0][3 * HID + 1] + red[1][3 * HID + 1] +
                          red[2][3 * HID + 1] + red[3][3 * HID + 1]);
    }
  }
}

__global__ void k_final(const float* __restrict__ add, const float* __restrict__ cnt,
                        const float* __restrict__ attp, const float* __restrict__ aden,
                        const unsigned* __restrict__ mxE, const float* __restrict__ lin1_w,
                        const float* __restrict__ lin1_b, const float* __restrict__ lin2_w,
                        const float* __restrict__ lin2_b, float* __restrict__ out) {
  __shared__ float pooled[4 * HID];
  __shared__ float zred[2 * HID];
  int g = blockIdx.x, t = threadIdx.x;  // 256 threads
  if (t < HID)            pooled[t] = add[g * HID + t];
  else if (t < 2 * HID)   pooled[t] = add[g * HID + (t - HID)] / fmaxf(cnt[g], 1.f);
  else if (t < 3 * HID)   pooled[t] = attp[g * HID + (t - 2 * HID)] / (aden[g] + 1e-16f);
  else                    pooled[t] = fdec(mxE[g * HID + (t - 3 * HID)]);
  __syncthreads();
  if (t < 2 * HID) {
    float z = lin1_b[t];
    for (int k = 0; k < 4 * HID; k++) z += pooled[k] * lin1_w[k * (2 * HID) + t];
    z = tanhf(z);
    zred[t] = z * lin2_w[t];
  }
  __syncthreads();
  if (t == 0) {
    float s = 0.f;
    for (int k = 0; k < 2 * HID; k++) s += zred[k];
    out[g] = s + lin2_b[0];
  }
}

extern "C" void kernel_launch(void* const* d_in, const int* in_sizes, int n_in,
                              void* d_out, int out_size, void* d_ws, size_t ws_size,
                              hipStream_t stream) {
  const float* x      = (const float*)d_in[0];
  const int*   ei     = (const int*)d_in[1];
  const float* eattr  = (const float*)d_in[2];
  const int*   batch  = (const int*)d_in[3];
  const int*   ipos   = (const int*)d_in[4];
  // d_in[5] = graph_num scalar (G=50, hardcoded)
  const float* W0     = (const float*)d_in[6];
  const float* attl0  = (const float*)d_in[7];
  const float* attr0  = (const float*)d_in[8];
  const float* W12    = (const float*)d_in[9];
  const float* attl12 = (const float*)d_in[10];
  const float* attr12 = (const float*)d_in[11];
  const float* eW     = (const float*)d_in[12];
  const float* eb     = (const float*)d_in[13];
  const float* bconv  = (const float*)d_in[14];
  const float* gate_w = (const float*)d_in[15];
  const float* gate_b = (const float*)d_in[16];
  const float* lin1_w = (const float*)d_in[17];
  const float* lin1_b = (const float*)d_in[18];
  const float* lin2_w = (const float*)d_in[19];
  const float* lin2_b = (const float*)d_in[20];
  float* out = (float*)d_out;

  char* ws = (char*)d_ws;
  size_t off = 0;
  auto alloc = [&](size_t elems) {
    void* p = ws + off;
    off += ((elems * 4 + 15) / 16) * 16;   // 16B-aligned slots
    return p;
  };
  // ---- zero-init region (contiguous, one memset) ----
  int*      deg    = (int*)alloc(N_NODES);
  int*      gcur   = (int*)alloc(4);
  float*    addp   = (float*)alloc(NG * HID);
  float*    attp   = (float*)alloc(NG * HID);
  unsigned* mxE    = (unsigned*)alloc(NG * HID);
  float*    cnt    = (float*)alloc(64);
  float*    aden   = (float*)alloc(64);
  size_t zbytes = off;
  // ---- rest ----
  int*     gstart = (int*)alloc(NG + 4);
  int*     start  = (int*)alloc(N_NODES);
  int*     rank   = (int*)alloc(NET);
  int2*    erec   = (int2*)alloc((size_t)NET * 2);           // 8B records
  __half2* xl2h   = (__half2*)alloc((size_t)N_NODES * HID);  // 4B each
  float*   al     = (float*)alloc((size_t)N_NODES * 2);
  float*   arr    = (float*)alloc((size_t)N_NODES * 2);
  float*   h0     = (float*)alloc((size_t)N_NODES * HID);
  float*   h1     = (float*)alloc((size_t)N_NODES * HID);
  float*   h2     = (float*)alloc((size_t)N_NODES * HID);
  (void)ws_size; (void)in_sizes; (void)n_in; (void)out_size;

  hipMemsetAsync(d_ws, 0, zbytes, stream);
  k_hist_ranges<<<HBLK + (NI + 255) / 256, 256, 0, stream>>>(ei, deg, rank, ipos, batch, gstart);
  k_base<<<(N_NODES + 255) / 256, 256, 0, stream>>>(deg, start, gcur);
  k_scatter<<<(NET + 255) / 256, 256, 0, stream>>>(ei, eattr, start, rank, erec);

  // layer 0
  k_linear_mfma<FIN><<<N_NODES / 16, 256, 0, stream>>>(x, W0, attl0, attr0, xl2h, al, arr);
  k_aggregate<<<N_NODES / 8, 256, 0, stream>>>(xl2h, al, (const float2*)arr,
                                               start, deg, erec, eW, eb, bconv, h0);
  // layer 1
  k_linear_mfma<HID><<<N_NODES / 16, 256, 0, stream>>>(h0, W12, attl12, attr12, xl2h, al, arr);
  k_aggregate<<<N_NODES / 8, 256, 0, stream>>>(xl2h, al, (const float2*)arr,
                                               start, deg, erec, eW + 2 * HC, eb + HC,
                                               bconv + HID, h1);
  // layer 2
  k_linear_mfma<HID><<<N_NODES / 16, 256, 0, stream>>>(h1, W12 + (size_t)HID * HC,
                                                       attl12 + HC, attr12 + HC, xl2h, al, arr);
  k_aggregate<<<N_NODES / 8, 256, 0, stream>>>(xl2h, al, (const float2*)arr,
                                               start, deg, erec, eW + 4 * HC, eb + 2 * HC,
                                               bconv + 2 * HID, h2);

  k_pool<<<NG * PB, 256, 0, stream>>>(h0, h1, h2, ipos, gstart, gate_w, gate_b,
                                      addp, mxE, cnt, attp, aden);
  k_final<<<NG, 256, 0, stream>>>(addp, cnt, attp, aden, mxE, lin1_w, lin1_b, lin2_w, lin2_b, out);
}